// Round 1
// baseline (380764.526 us; speedup 1.0000x reference)
//
#include <hip/hip_runtime.h>
#include <hip/hip_cooperative_groups.h>
#include <math.h>

namespace cg = cooperative_groups;

constexpr int T = 4096;   // SEQ_LEN
constexpr int R = 2048;   // RES_SIZE
constexpr int J = 128;    // INPUT_SIZE
constexpr float ONE_MINUS_LEAK = 0.1f;
constexpr float LEAK = 0.9f;
constexpr float INV_SQRT_R = 0.022097086912079608f;  // 1/sqrt(2048)

// ---------------- Kernel A: proj[t][r] = input[t] . W_in[r] + bias[r] -> d_out
__global__ __launch_bounds__(256) void esn_proj_kernel(
    const float* __restrict__ U, const float* __restrict__ Win,
    const float* __restrict__ bias, float* __restrict__ out)
{
    __shared__ float As[16][129];   // +1 pad: conflict-free
    __shared__ float Bs[16][129];
    const int tb = blockIdx.x * 16;
    const int rb = blockIdx.y * 16;
    const int tid = threadIdx.x;

    for (int i = tid; i < 16 * J; i += 256) {
        int r = i >> 7, c = i & 127;
        As[r][c] = U[(size_t)(tb + r) * J + c];
        Bs[r][c] = Win[(size_t)(rb + r) * J + c];
    }
    __syncthreads();

    const int ti = tid >> 4;
    const int rj = tid & 15;
    float acc = 0.f;
#pragma unroll
    for (int k = 0; k < J; ++k) acc = fmaf(As[ti][k], Bs[rj][k], acc);
    out[(size_t)(tb + ti) * R + (rb + rj)] = acc + bias[rb + rj];
}

// ---------------- Kernel B: persistent cooperative recurrence
// 256 WGs x 512 threads. WG w owns rows [8w, 8w+8); wave v owns row 8w+v.
// Weights in registers: lane L holds W_res[row][k*64+L], k=0..31.
__global__ __launch_bounds__(512, 2) void esn_recur_kernel(
    const float* __restrict__ Wres, float* __restrict__ out,
    float* __restrict__ xbuf /* 2*R floats, double buffer */)
{
    const int wg   = blockIdx.x;     // 0..255
    const int tid  = threadIdx.x;    // 0..511
    const int wave = tid >> 6;       // 0..7
    const int lane = tid & 63;
    const int row  = wg * 8 + wave;

    // Preload this row's weights into registers (coalesced: 64 lanes x f32 per k)
    float w[32];
    {
        const float* wr = Wres + (size_t)row * R + lane;
#pragma unroll
        for (int k = 0; k < 32; ++k) w[k] = wr[k * 64];
    }

    __shared__ float xs[R];

    cg::grid_group grid = cg::this_grid();

    for (int t = 0; t < T; ++t) {
        const float* xsrc = xbuf + (size_t)(t & 1) * R;
        float* xdst       = xbuf + (size_t)((t + 1) & 1) * R;

        // Stage current state into LDS (512 threads x 4 elems, coalesced)
#pragma unroll
        for (int i = 0; i < 4; ++i) xs[tid + i * 512] = xsrc[tid + i * 512];
        __syncthreads();

        // Issue the scalar loads early so their latency hides under the dot.
        float proj = 0.f, xold = 0.f;
        if (lane == 0) {
            proj = out[(size_t)t * R + row];   // input projection (precomputed)
            xold = xs[row];                    // previous state of this row
        }

        // Row dot product: 32 conflict-free LDS reads + FMAs per lane
        float acc = 0.f;
#pragma unroll
        for (int k = 0; k < 32; ++k) acc = fmaf(w[k], xs[k * 64 + lane], acc);

        // Wave (64-lane) shuffle reduction
#pragma unroll
        for (int off = 32; off > 0; off >>= 1) acc += __shfl_down(acc, off);

        if (lane == 0) {
            float pre  = acc + proj;           // RES_SCALE = INPUT_SCALE = 1
            float xnew = ONE_MINUS_LEAK * xold + LEAK * erff(pre) * INV_SQRT_R;
            out[(size_t)t * R + row] = xnew;   // states output (overwrites proj)
            xdst[row] = xnew;                  // broadcast buffer for next step
        }

        // Make xdst visible device-wide (per-XCD L2s are non-coherent),
        // then wait for everyone, then invalidate local caches.
        __threadfence();
        grid.sync();
        __threadfence();
    }
}

extern "C" void kernel_launch(void* const* d_in, const int* in_sizes, int n_in,
                              void* d_out, int out_size, void* d_ws, size_t ws_size,
                              hipStream_t stream) {
    const float* U    = (const float*)d_in[0];  // (4096,128)
    const float* Win  = (const float*)d_in[1];  // (2048,128)
    const float* Wres = (const float*)d_in[2];  // (2048,2048)
    const float* bias = (const float*)d_in[3];  // (2048,)
    float* out  = (float*)d_out;                // (4096,2048)
    float* xbuf = (float*)d_ws;                 // 2*2048 f32 double buffer

    // x0 = 0 (deterministic per call; harness does not re-zero ws between replays)
    hipMemsetAsync(d_ws, 0, 2 * R * sizeof(float), stream);

    // Input projection -> d_out
    dim3 pgrid(T / 16, R / 16);
    esn_proj_kernel<<<pgrid, dim3(256), 0, stream>>>(U, Win, bias, out);

    // Persistent cooperative recurrence
    void* args[] = { (void*)&Wres, (void*)&out, (void*)&xbuf };
    hipLaunchCooperativeKernel((const void*)esn_recur_kernel,
                               dim3(256), dim3(512), args, 0, stream);
}

// Round 2
// 15397.029 us; speedup vs baseline: 24.7297x; 24.7297x over previous
//
#include <hip/hip_runtime.h>
#include <hip/hip_cooperative_groups.h>
#include <math.h>

constexpr int T = 4096;   // SEQ_LEN
constexpr int R = 2048;   // RES_SIZE
constexpr int J = 128;    // INPUT_SIZE
constexpr float ONE_MINUS_LEAK = 0.1f;
constexpr float LEAK = 0.9f;
constexpr float INV_SQRT_R = 0.022097086912079608f;  // 1/sqrt(2048)

constexpr int NWG = 256;        // one WG per CU
constexpr int FLAG_STRIDE = 16; // u32s -> 64 B per flag line

// ---------------- Kernel A: proj[t][r] = input[t] . W_in[r] + bias[r] -> d_out
__global__ __launch_bounds__(256) void esn_proj_kernel(
    const float* __restrict__ U, const float* __restrict__ Win,
    const float* __restrict__ bias, float* __restrict__ out)
{
    __shared__ float As[16][129];
    __shared__ float Bs[16][129];
    const int tb = blockIdx.x * 16;
    const int rb = blockIdx.y * 16;
    const int tid = threadIdx.x;

    for (int i = tid; i < 16 * J; i += 256) {
        int r = i >> 7, c = i & 127;
        As[r][c] = U[(size_t)(tb + r) * J + c];
        Bs[r][c] = Win[(size_t)(rb + r) * J + c];
    }
    __syncthreads();

    const int ti = tid >> 4;
    const int rj = tid & 15;
    float acc = 0.f;
#pragma unroll
    for (int k = 0; k < J; ++k) acc = fmaf(As[ti][k], Bs[rj][k], acc);
    out[(size_t)(tb + ti) * R + (rb + rj)] = acc + bias[rb + rj];
}

// ---------------- Kernel B: persistent recurrence with flag barrier
// 256 WGs x 512 threads. WG w owns rows [8w, 8w+8); wave v owns row 8w+v.
// Cross-WG traffic uses agent-scope atomics (sc1: per-access coherent,
// no cache-wide buffer_inv/wbl2). flags[w]=k means WG w completed step k-1.
__global__ __launch_bounds__(512, 2) void esn_recur_kernel(
    const float* __restrict__ Wres, float* __restrict__ out,
    float* __restrict__ ws)
{
    const int wg   = blockIdx.x;     // 0..255
    const int tid  = threadIdx.x;    // 0..511
    const int wave = tid >> 6;       // 0..7
    const int lane = tid & 63;
    const int row  = wg * 8 + wave;

    float*    xbuf  = ws;                         // [2][R] double buffer
    unsigned* flags = (unsigned*)(ws + 2 * R);    // NWG lines, 64 B apart

    // Row weights in registers (coalesced: 64 lanes x f32 per k)
    float w[32];
    {
        const float* wr = Wres + (size_t)row * R + lane;
#pragma unroll
        for (int k = 0; k < 32; ++k) w[k] = wr[k * 64];
    }

    __shared__ float xs[R];
    float xold = 0.f;                 // this row's previous state (lane 0 uses)

    for (int t = 0; t < T; ++t) {
        // Prefetch input projection early (plain load, kernel-A data).
        float proj = 0.f;
        if (lane == 0) proj = out[(size_t)t * R + row];

        // Barrier: wait until every WG has completed step t-1.
        if (t > 0) {
            if (wave == 0) {
                const unsigned tgt = (unsigned)t;
                bool ok = false;
                while (!ok) {
                    bool mine = true;
#pragma unroll
                    for (int i = 0; i < 4; ++i) {
                        unsigned f = __hip_atomic_load(
                            &flags[(lane + i * 64) * FLAG_STRIDE],
                            __ATOMIC_RELAXED, __HIP_MEMORY_SCOPE_AGENT);
                        mine &= (f >= tgt);
                    }
                    ok = __all(mine);
                    if (!ok) __builtin_amdgcn_s_sleep(1);
                }
            }
            __syncthreads();
        }

        // Stage x_{t-1} into LDS via coherent loads (bypass stale L2).
        const float* xsrc = xbuf + (size_t)(t & 1) * R;
#pragma unroll
        for (int i = 0; i < 4; ++i) {
            int idx = tid + i * 512;
            xs[idx] = __hip_atomic_load(&xsrc[idx], __ATOMIC_RELAXED,
                                        __HIP_MEMORY_SCOPE_AGENT);
        }
        __syncthreads();

        // Row dot product: 32 conflict-free LDS reads + FMAs per lane.
        float acc = 0.f;
#pragma unroll
        for (int k = 0; k < 32; ++k) acc = fmaf(w[k], xs[k * 64 + lane], acc);
#pragma unroll
        for (int off = 32; off > 0; off >>= 1) acc += __shfl_down(acc, off);

        float* xdst = xbuf + (size_t)((t + 1) & 1) * R;
        if (lane == 0) {
            float pre  = acc + proj;   // RES_SCALE = INPUT_SCALE = 1
            float xnew = ONE_MINUS_LEAK * xold + LEAK * erff(pre) * INV_SQRT_R;
            xold = xnew;
            out[(size_t)t * R + row] = xnew;            // states output
            __hip_atomic_store(&xdst[row], xnew, __ATOMIC_RELAXED,
                               __HIP_MEMORY_SCOPE_AGENT);
        }
        // Wave-level: own sc1 store complete; then WG-level join; then publish.
        asm volatile("s_waitcnt vmcnt(0)" ::: "memory");
        __syncthreads();
        if (tid == 0)
            __hip_atomic_store(&flags[wg * FLAG_STRIDE], (unsigned)(t + 1),
                               __ATOMIC_RELAXED, __HIP_MEMORY_SCOPE_AGENT);
    }
}

extern "C" void kernel_launch(void* const* d_in, const int* in_sizes, int n_in,
                              void* d_out, int out_size, void* d_ws, size_t ws_size,
                              hipStream_t stream) {
    const float* U    = (const float*)d_in[0];  // (4096,128)
    const float* Win  = (const float*)d_in[1];  // (2048,128)
    const float* Wres = (const float*)d_in[2];  // (2048,2048)
    const float* bias = (const float*)d_in[3];  // (2048,)
    float* out = (float*)d_out;                 // (4096,2048)
    float* ws  = (float*)d_ws;

    // Zero x0 double buffer (16 KB) + flags (16 KB); graph-replay safe.
    hipMemsetAsync(d_ws, 0, (2 * R + NWG * FLAG_STRIDE) * sizeof(float), stream);

    dim3 pgrid(T / 16, R / 16);
    esn_proj_kernel<<<pgrid, dim3(256), 0, stream>>>(U, Win, bias, out);

    void* args[] = { (void*)&Wres, (void*)&out, (void*)&ws };
    hipLaunchCooperativeKernel((const void*)esn_recur_kernel,
                               dim3(NWG), dim3(512), args, 0, stream);
}